// Round 6
// baseline (262.515 us; speedup 1.0000x reference)
//
#include <hip/hip_runtime.h>
#include <hip/hip_bf16.h>

#define D 128
#define NCLS 10

static __device__ __forceinline__ float relu(float x){ return fmaxf(x, 0.0f); }
static __device__ __forceinline__ float bf_lo(unsigned v){ return __uint_as_float(v << 16); }
static __device__ __forceinline__ float bf_hi(unsigned v){ return __uint_as_float(v & 0xffff0000u); }

__global__ __launch_bounds__(256) void k_zero_i32(int* __restrict__ p, int n){
  int i = blockIdx.x*256 + threadIdx.x;
  if (i < n) p[i] = 0;
}

__global__ __launch_bounds__(256) void k_hist(const int* __restrict__ dst,
                                              int* __restrict__ counts, int E){
  int i = blockIdx.x*256 + threadIdx.x;
  if (i < E) atomicAdd(counts + dst[i], 1);
}

// per-block exclusive scan of counts -> rowPtr (block-local), block sums; fused dinv
__global__ __launch_bounds__(256) void k_scan1(const int* __restrict__ counts,
                                               int* __restrict__ rowPtr,
                                               int* __restrict__ bsum,
                                               float* __restrict__ dinv, int n){
  const int i = blockIdx.x*256 + threadIdx.x;
  const int lane = threadIdx.x & 63;
  const int wid  = threadIdx.x >> 6;
  int v = (i < n) ? counts[i] : 0;
  if (i < n) dinv[i] = rsqrtf((float)(v + 1));   // +1 self-loop
  int s = v;
  #pragma unroll
  for (int off = 1; off < 64; off <<= 1){
    int u = __shfl_up(s, off, 64);
    if (lane >= off) s += u;
  }
  __shared__ int ws[4];
  if (lane == 63) ws[wid] = s;
  __syncthreads();
  int add = 0;
  if (wid >= 1) add += ws[0];
  if (wid >= 2) add += ws[1];
  if (wid >= 3) add += ws[2];
  int incl = s + add;
  if (i < n) rowPtr[i] = incl - v;
  if (threadIdx.x == 255) bsum[blockIdx.x] = incl;
}

__global__ __launch_bounds__(256) void k_scan2(int* __restrict__ bsum,
                                               int* __restrict__ rowPtr,
                                               int nb, int n){
  const int t = threadIdx.x;
  const int lane = t & 63;
  const int wid  = t >> 6;
  int v = (t < nb) ? bsum[t] : 0;
  int s = v;
  #pragma unroll
  for (int off = 1; off < 64; off <<= 1){
    int u = __shfl_up(s, off, 64);
    if (lane >= off) s += u;
  }
  __shared__ int ws[4];
  if (lane == 63) ws[wid] = s;
  __syncthreads();
  int add = 0;
  if (wid >= 1) add += ws[0];
  if (wid >= 2) add += ws[1];
  if (wid >= 3) add += ws[2];
  int incl = s + add;
  if (t < nb) bsum[t] = incl - v;
  if (t == 255) rowPtr[n] = incl;
}

__global__ __launch_bounds__(256) void k_scan3(const int* __restrict__ bsum,
                                               int* __restrict__ rowPtr, int n){
  int i = blockIdx.x*256 + threadIdx.x;
  if (i < n) rowPtr[i] += bsum[blockIdx.x];
}

// scatter edge -> CSR slot; store {src, dinv[src]} as int2 (one 8B unit)
__global__ __launch_bounds__(256) void k_scatter(const int* __restrict__ src,
                                                 const int* __restrict__ dst,
                                                 const int* __restrict__ rowPtr,
                                                 const float* __restrict__ dinv,
                                                 int* __restrict__ cursor,
                                                 int2* __restrict__ edat, int E){
  int i = blockIdx.x*256 + threadIdx.x;
  if (i >= E) return;
  int d = dst[i];
  int s = src[i];
  int pos = rowPtr[d] + atomicAdd(cursor + d, 1);
  edat[pos] = make_int2(s, __float_as_int(dinv[s]));
}

// C(bf16) = maybe_relu(A) @ W(f32); A f32 or bf16 per template.
template<bool BF16IN>
__global__ __launch_bounds__(256) void k_gemm128(const void* __restrict__ Av,
                                                 const float* __restrict__ W,
                                                 __hip_bfloat16* __restrict__ C,
                                                 int M, int doRelu){
  __shared__ float4 sW4[64*32];   // [k_local][c4]  32KB
  __shared__ float4 sA4[32*33];   // padded row stride 33 float4
  const int tid = threadIdx.x;
  const int row0 = blockIdx.x * 32;
  const int rowsHere = (M - row0 >= 32) ? 32 : (M - row0);
  if (BF16IN){
    const uint4* A8 = (const uint4*)((const ushort*)Av + (size_t)row0 * D);
    // 32 rows x 16 uint4 (8 bf16 each) = 512 items
    for (int i = tid; i < 32*16; i += 256){
      int r = i >> 4, c8 = i & 15;
      float4 lo = make_float4(0,0,0,0), hi = lo;
      if (r < rowsHere){
        uint4 v = A8[i];
        lo.x = bf_lo(v.x); lo.y = bf_hi(v.x); lo.z = bf_lo(v.y); lo.w = bf_hi(v.y);
        hi.x = bf_lo(v.z); hi.y = bf_hi(v.z); hi.z = bf_lo(v.w); hi.w = bf_hi(v.w);
        if (doRelu){
          lo.x=relu(lo.x); lo.y=relu(lo.y); lo.z=relu(lo.z); lo.w=relu(lo.w);
          hi.x=relu(hi.x); hi.y=relu(hi.y); hi.z=relu(hi.z); hi.w=relu(hi.w);
        }
      }
      sA4[r*33 + 2*c8]     = lo;
      sA4[r*33 + 2*c8 + 1] = hi;
    }
  } else {
    const float4* A4 = (const float4*)Av + (size_t)row0 * 32;
    const int nf4 = rowsHere * 32;
    for (int i = tid; i < 32*32; i += 256){
      float4 v = make_float4(0.f, 0.f, 0.f, 0.f);
      if (i < nf4) v = A4[i];
      if (doRelu){ v.x=relu(v.x); v.y=relu(v.y); v.z=relu(v.z); v.w=relu(v.w); }
      sA4[(i >> 5)*33 + (i & 31)] = v;
    }
  }
  const int colg = tid & 15;
  const int rowg = tid >> 4;
  float4 acc00 = make_float4(0,0,0,0), acc01 = acc00, acc10 = acc00, acc11 = acc00;
  for (int ph = 0; ph < 2; ++ph){
    __syncthreads();
    const float4* Wp = (const float4*)W + ph * (64*32);
    #pragma unroll
    for (int i = 0; i < 8; ++i) sW4[i*256 + tid] = Wp[i*256 + tid];
    __syncthreads();
    #pragma unroll 4
    for (int k4 = 0; k4 < 16; ++k4){
      float4 a0 = sA4[(2*rowg)*33   + ph*16 + k4];
      float4 a1 = sA4[(2*rowg+1)*33 + ph*16 + k4];
      #pragma unroll
      for (int kk = 0; kk < 4; ++kk){
        const int k = k4*4 + kk;
        float4 w0 = sW4[k*32 + colg];
        float4 w1 = sW4[k*32 + colg + 16];
        float av0 = ((const float*)&a0)[kk];
        float av1 = ((const float*)&a1)[kk];
        acc00.x += av0*w0.x; acc00.y += av0*w0.y; acc00.z += av0*w0.z; acc00.w += av0*w0.w;
        acc01.x += av0*w1.x; acc01.y += av0*w1.y; acc01.z += av0*w1.z; acc01.w += av0*w1.w;
        acc10.x += av1*w0.x; acc10.y += av1*w0.y; acc10.z += av1*w0.z; acc10.w += av1*w0.w;
        acc11.x += av1*w1.x; acc11.y += av1*w1.y; acc11.z += av1*w1.z; acc11.w += av1*w1.w;
      }
    }
  }
  union Pack { ushort4 u; __hip_bfloat16 b[4]; };
  ushort4* C4 = (ushort4*)C;
  const int r0 = row0 + 2*rowg;
  if (r0 < M){
    Pack p0, p1;
    p0.b[0]=__float2bfloat16(acc00.x); p0.b[1]=__float2bfloat16(acc00.y);
    p0.b[2]=__float2bfloat16(acc00.z); p0.b[3]=__float2bfloat16(acc00.w);
    p1.b[0]=__float2bfloat16(acc01.x); p1.b[1]=__float2bfloat16(acc01.y);
    p1.b[2]=__float2bfloat16(acc01.z); p1.b[3]=__float2bfloat16(acc01.w);
    C4[(size_t)r0*32 + colg]      = p0.u;
    C4[(size_t)r0*32 + colg + 16] = p1.u;
  }
  if (r0 + 1 < M){
    Pack p0, p1;
    p0.b[0]=__float2bfloat16(acc10.x); p0.b[1]=__float2bfloat16(acc10.y);
    p0.b[2]=__float2bfloat16(acc10.z); p0.b[3]=__float2bfloat16(acc10.w);
    p1.b[0]=__float2bfloat16(acc11.x); p1.b[1]=__float2bfloat16(acc11.y);
    p1.b[2]=__float2bfloat16(acc11.z); p1.b[3]=__float2bfloat16(acc11.w);
    C4[(size_t)(r0+1)*32 + colg]      = p0.u;
    C4[(size_t)(r0+1)*32 + colg + 16] = p1.u;
  }
}

// bf16 gather core: 4 edges/step (16 lanes x uint4 = 256B row each), unroll 4,
// edge meta {src,norm} preloaded as int2 (no random scalar gather).
// After macro: grp-reduced f32 sums for elems [8q..8q+7] in rA,rB (all lanes).
#define AGG_CORE_BF16                                                          \
  const int grp = lane >> 4;                                                   \
  const int q   = lane & 15;                                                   \
  float dn = dinv[node];                                                       \
  float4 aA0 = make_float4(0,0,0,0), aB0 = aA0;                                \
  float4 aA1 = aA0, aB1 = aA0, aA2 = aA0, aB2 = aA0, aA3 = aA0, aB3 = aA0;     \
  int beg = rowPtr[node], end = rowPtr[node+1];                                \
  for (int j = beg; j < end; j += 64){                                         \
    int rem = end - j;                                                         \
    int cnt = (rem < 64) ? rem : 64;                                           \
    int2 ed = make_int2(0, 0);                                                 \
    if (lane < cnt) ed = edat[j + lane];                                       \
    int T = (((cnt + 3) >> 2) + 3) & ~3;                                       \
    for (int t = 0; t < T; t += 4){                                            \
      _Pragma("unroll")                                                        \
      for (int u = 0; u < 4; ++u){                                             \
        int e = 4*(t+u) + grp;                                                 \
        int sb = __shfl(ed.x, e);                                              \
        float nb = __uint_as_float((unsigned)__shfl(ed.y, e)) * dn;            \
        uint4 hv = ((const uint4*)(h + (size_t)sb*D))[q];                      \
        float4& cA = (u==0)?aA0:(u==1)?aA1:(u==2)?aA2:aA3;                     \
        float4& cB = (u==0)?aB0:(u==1)?aB1:(u==2)?aB2:aB3;                     \
        cA.x += bf_lo(hv.x)*nb; cA.y += bf_hi(hv.x)*nb;                        \
        cA.z += bf_lo(hv.y)*nb; cA.w += bf_hi(hv.y)*nb;                        \
        cB.x += bf_lo(hv.z)*nb; cB.y += bf_hi(hv.z)*nb;                        \
        cB.z += bf_lo(hv.w)*nb; cB.w += bf_hi(hv.w)*nb;                        \
      }                                                                        \
    }                                                                          \
  }                                                                            \
  float4 rA, rB;                                                               \
  rA.x=(aA0.x+aA1.x)+(aA2.x+aA3.x); rA.y=(aA0.y+aA1.y)+(aA2.y+aA3.y);          \
  rA.z=(aA0.z+aA1.z)+(aA2.z+aA3.z); rA.w=(aA0.w+aA1.w)+(aA2.w+aA3.w);          \
  rB.x=(aB0.x+aB1.x)+(aB2.x+aB3.x); rB.y=(aB0.y+aB1.y)+(aB2.y+aB3.y);          \
  rB.z=(aB0.z+aB1.z)+(aB2.z+aB3.z); rB.w=(aB0.w+aB1.w)+(aB2.w+aB3.w);          \
  rA.x += __shfl_xor(rA.x,16,64); rA.y += __shfl_xor(rA.y,16,64);              \
  rA.z += __shfl_xor(rA.z,16,64); rA.w += __shfl_xor(rA.w,16,64);              \
  rB.x += __shfl_xor(rB.x,16,64); rB.y += __shfl_xor(rB.y,16,64);              \
  rB.z += __shfl_xor(rB.z,16,64); rB.w += __shfl_xor(rB.w,16,64);              \
  rA.x += __shfl_xor(rA.x,32,64); rA.y += __shfl_xor(rA.y,32,64);              \
  rA.z += __shfl_xor(rA.z,32,64); rA.w += __shfl_xor(rA.w,32,64);              \
  rB.x += __shfl_xor(rB.x,32,64); rB.y += __shfl_xor(rB.y,32,64);              \
  rB.z += __shfl_xor(rB.z,32,64); rB.w += __shfl_xor(rB.w,32,64);

// layer-1 agg: out(bf16)[node] = h*dinv^2 + b + gathered
__global__ __launch_bounds__(256) void k_agg_csr(const ushort* __restrict__ h,
                                                 const int* __restrict__ rowPtr,
                                                 const int2* __restrict__ edat,
                                                 const float* __restrict__ dinv,
                                                 const float* __restrict__ b,
                                                 ushort* __restrict__ out, int n){
  int gid = blockIdx.x*256 + threadIdx.x;
  int node = gid >> 6;
  int lane = gid & 63;
  if (node >= n) return;
  AGG_CORE_BF16
  if (grp != 0) return;
  uint4 hs = ((const uint4*)(h + (size_t)node*D))[q];
  float sl = dn * dn;
  float4 bA = ((const float4*)b)[2*q];
  float4 bB = ((const float4*)b)[2*q + 1];
  float r[8];
  r[0] = rA.x + bf_lo(hs.x)*sl + bA.x;
  r[1] = rA.y + bf_hi(hs.x)*sl + bA.y;
  r[2] = rA.z + bf_lo(hs.y)*sl + bA.z;
  r[3] = rA.w + bf_hi(hs.y)*sl + bA.w;
  r[4] = rB.x + bf_lo(hs.z)*sl + bB.x;
  r[5] = rB.y + bf_hi(hs.z)*sl + bB.y;
  r[6] = rB.z + bf_lo(hs.w)*sl + bB.z;
  r[7] = rB.w + bf_hi(hs.w)*sl + bB.w;
  union Pack { uint4 u; __hip_bfloat16 b[8]; } p;
  #pragma unroll
  for (int i = 0; i < 8; ++i) p.b[i] = __float2bfloat16(r[i]);
  ((uint4*)(out + (size_t)node*D))[q] = p.u;
}

// layer-2 agg fused with head: relu(agg) @ Wl + bl -> log_softmax
__global__ __launch_bounds__(256) void k_agg_head(const ushort* __restrict__ h,
                                                  const int* __restrict__ rowPtr,
                                                  const int2* __restrict__ edat,
                                                  const float* __restrict__ dinv,
                                                  const float* __restrict__ b,
                                                  const float* __restrict__ Wl,
                                                  const float* __restrict__ bl,
                                                  float* __restrict__ out, int n){
  int gid = blockIdx.x*256 + threadIdx.x;
  int node = gid >> 6;
  int lane = gid & 63;
  if (node >= n) return;
  AGG_CORE_BF16
  if (grp != 0) return;
  uint4 hs = ((const uint4*)(h + (size_t)node*D))[q];
  float sl = dn * dn;
  float4 bA = ((const float4*)b)[2*q];
  float4 bB = ((const float4*)b)[2*q + 1];
  float r[8];
  r[0] = relu(rA.x + bf_lo(hs.x)*sl + bA.x);
  r[1] = relu(rA.y + bf_hi(hs.x)*sl + bA.y);
  r[2] = relu(rA.z + bf_lo(hs.y)*sl + bA.z);
  r[3] = relu(rA.w + bf_hi(hs.y)*sl + bA.w);
  r[4] = relu(rB.x + bf_lo(hs.z)*sl + bB.x);
  r[5] = relu(rB.y + bf_hi(hs.z)*sl + bB.y);
  r[6] = relu(rB.z + bf_lo(hs.w)*sl + bB.z);
  r[7] = relu(rB.w + bf_hi(hs.w)*sl + bB.w);
  float lacc[NCLS];
  #pragma unroll
  for (int c = 0; c < NCLS; ++c){
    float a = 0.f;
    #pragma unroll
    for (int i = 0; i < 8; ++i) a += r[i] * Wl[(8*q + i)*NCLS + c];
    lacc[c] = a;
  }
  #pragma unroll
  for (int c = 0; c < NCLS; ++c){
    #pragma unroll
    for (int off = 8; off >= 1; off >>= 1)
      lacc[c] += __shfl_xor(lacc[c], off, 16);
    lacc[c] += bl[c];
  }
  float m = lacc[0];
  #pragma unroll
  for (int c = 1; c < NCLS; ++c) m = fmaxf(m, lacc[c]);
  float se = 0.f;
  #pragma unroll
  for (int c = 0; c < NCLS; ++c) se += expf(lacc[c] - m);
  float lse = m + logf(se);
  if (q < NCLS){
    float v = lacc[0];
    #pragma unroll
    for (int c = 1; c < NCLS; ++c) if (q == c) v = lacc[c];
    out[(size_t)node*NCLS + q] = v - lse;
  }
}

extern "C" void kernel_launch(void* const* d_in, const int* in_sizes, int n_in,
                              void* d_out, int out_size, void* d_ws, size_t ws_size,
                              hipStream_t stream){
  const float* x  = (const float*)d_in[0];
  const int*   ei = (const int*)d_in[1];
  const float* W1 = (const float*)d_in[2];
  const float* b1 = (const float*)d_in[3];
  const float* W2 = (const float*)d_in[4];
  const float* b2 = (const float*)d_in[5];
  const float* Wl = (const float*)d_in[6];
  const float* bl = (const float*)d_in[7];
  float* out = (float*)d_out;

  const int N = in_sizes[0] / D;     // 50000
  const int E = in_sizes[1] / 2;     // 800000
  const int* src = ei;
  const int* dst = ei + E;

  char* ws = (char*)d_ws;
  size_t off = 0;
  ushort* h1    = (ushort*)(ws + off); off += (size_t)N*D*2;   // GEMM1 out (bf16)
  ushort* g1    = (ushort*)(ws + off); off += (size_t)N*D*2;   // agg1 out  (bf16)
  ushort* h2    = (ushort*)(ws + off); off += (size_t)N*D*2;   // GEMM2 out (bf16)
  int*   counts = (int*)(ws + off);    off += (size_t)N*4;
  int*   cursor = (int*)(ws + off);    off += (size_t)N*4;     // adjacent to counts
  int*   rowPtr = (int*)(ws + off);    off += (size_t)(N+1)*4;
  float* dinv   = (float*)(ws + off);  off += (size_t)N*4;
  int*   bsum   = (int*)(ws + off);    off += (size_t)256*4;
  int2*  edat   = (int2*)(ws + off);   off += (size_t)E*8;

  const int nbN   = (N + 255)/256;   // 196 <= 256
  const int nb2N  = (2*N + 255)/256;
  const int nbE   = (E + 255)/256;
  const int gemmB = (N + 31)/32;
  const int aggB  = (N + 3)/4;       // 1 wave per node

  // CSR build
  k_zero_i32<<<nb2N, 256, 0, stream>>>(counts, 2*N);           // counts + cursor
  k_hist<<<nbE, 256, 0, stream>>>(dst, counts, E);
  k_scan1<<<nbN, 256, 0, stream>>>(counts, rowPtr, bsum, dinv, N);
  k_scan2<<<1, 256, 0, stream>>>(bsum, rowPtr, nbN, N);
  k_scan3<<<nbN, 256, 0, stream>>>(bsum, rowPtr, N);
  k_scatter<<<nbE, 256, 0, stream>>>(src, dst, rowPtr, dinv, cursor, edat, E);

  // layer 1
  k_gemm128<false><<<gemmB, 256, 0, stream>>>(x, W1, (__hip_bfloat16*)h1, N, 0);
  k_agg_csr<<<aggB, 256, 0, stream>>>(h1, rowPtr, edat, dinv, b1, g1, N);

  // layer 2 (relu fused into GEMM bf16 A-load; head fused into aggregation)
  k_gemm128<true><<<gemmB, 256, 0, stream>>>(g1, W2, (__hip_bfloat16*)h2, N, 1);
  k_agg_head<<<aggB, 256, 0, stream>>>(h2, rowPtr, edat, dinv, b2, Wl, bl, out, N);
}

// Round 7
// 210.968 us; speedup vs baseline: 1.2443x; 1.2443x over previous
//
#include <hip/hip_runtime.h>
#include <hip/hip_bf16.h>

#define D 128
#define NCLS 10

typedef short bf16x8 __attribute__((ext_vector_type(8)));
typedef float f32x4 __attribute__((ext_vector_type(4)));

static __device__ __forceinline__ float relu(float x){ return fmaxf(x, 0.0f); }
static __device__ __forceinline__ float bf_lo(unsigned v){ return __uint_as_float(v << 16); }
static __device__ __forceinline__ float bf_hi(unsigned v){ return __uint_as_float(v & 0xffff0000u); }
static __device__ __forceinline__ ushort bf16u(float f){
  __hip_bfloat16 h = __float2bfloat16(f);
  return *reinterpret_cast<ushort*>(&h);
}
// relu on a packed pair of bf16 (zero any half with sign bit set)
static __device__ __forceinline__ unsigned relu_bf2(unsigned v){
  if (v & 0x00008000u) v &= 0xFFFF0000u;
  if (v & 0x80000000u) v &= 0x0000FFFFu;
  return v;
}

__global__ __launch_bounds__(256) void k_zero_i32(int* __restrict__ p, int n){
  int i = blockIdx.x*256 + threadIdx.x;
  if (i < n) p[i] = 0;
}

__global__ __launch_bounds__(256) void k_hist(const int* __restrict__ dst,
                                              int* __restrict__ counts, int E){
  int i = blockIdx.x*256 + threadIdx.x;
  if (i < E) atomicAdd(counts + dst[i], 1);
}

// per-block exclusive scan of counts -> rowPtr (block-local), block sums; fused dinv
__global__ __launch_bounds__(256) void k_scan1(const int* __restrict__ counts,
                                               int* __restrict__ rowPtr,
                                               int* __restrict__ bsum,
                                               float* __restrict__ dinv, int n){
  const int i = blockIdx.x*256 + threadIdx.x;
  const int lane = threadIdx.x & 63;
  const int wid  = threadIdx.x >> 6;
  int v = (i < n) ? counts[i] : 0;
  if (i < n) dinv[i] = rsqrtf((float)(v + 1));   // +1 self-loop
  int s = v;
  #pragma unroll
  for (int off = 1; off < 64; off <<= 1){
    int u = __shfl_up(s, off, 64);
    if (lane >= off) s += u;
  }
  __shared__ int ws[4];
  if (lane == 63) ws[wid] = s;
  __syncthreads();
  int add = 0;
  if (wid >= 1) add += ws[0];
  if (wid >= 2) add += ws[1];
  if (wid >= 3) add += ws[2];
  int incl = s + add;
  if (i < n) rowPtr[i] = incl - v;
  if (threadIdx.x == 255) bsum[blockIdx.x] = incl;
}

__global__ __launch_bounds__(256) void k_scan2(int* __restrict__ bsum,
                                               int* __restrict__ rowPtr,
                                               int nb, int n){
  const int t = threadIdx.x;
  const int lane = t & 63;
  const int wid  = t >> 6;
  int v = (t < nb) ? bsum[t] : 0;
  int s = v;
  #pragma unroll
  for (int off = 1; off < 64; off <<= 1){
    int u = __shfl_up(s, off, 64);
    if (lane >= off) s += u;
  }
  __shared__ int ws[4];
  if (lane == 63) ws[wid] = s;
  __syncthreads();
  int add = 0;
  if (wid >= 1) add += ws[0];
  if (wid >= 2) add += ws[1];
  if (wid >= 3) add += ws[2];
  int incl = s + add;
  if (t < nb) bsum[t] = incl - v;
  if (t == 255) rowPtr[n] = incl;
}

__global__ __launch_bounds__(256) void k_scan3(const int* __restrict__ bsum,
                                               int* __restrict__ rowPtr, int n){
  int i = blockIdx.x*256 + threadIdx.x;
  if (i < n) rowPtr[i] += bsum[blockIdx.x];
}

// scatter edge -> CSR slot; store {src, dinv[src]} as int2
__global__ __launch_bounds__(256) void k_scatter(const int* __restrict__ src,
                                                 const int* __restrict__ dst,
                                                 const int* __restrict__ rowPtr,
                                                 const float* __restrict__ dinv,
                                                 int* __restrict__ cursor,
                                                 int2* __restrict__ edat, int E){
  int i = blockIdx.x*256 + threadIdx.x;
  if (i >= E) return;
  int d = dst[i];
  int s = src[i];
  int pos = rowPtr[d] + atomicAdd(cursor + d, 1);
  edat[pos] = make_int2(s, __float_as_int(dinv[s]));
}

// transpose+convert both weights: Wt[n][k] (bf16) = W[k][n] (f32); 2x128x128
__global__ __launch_bounds__(256) void k_cvtW(const float* __restrict__ W1,
                                              const float* __restrict__ W2,
                                              ushort* __restrict__ Wt1,
                                              ushort* __restrict__ Wt2){
  int i = blockIdx.x*256 + threadIdx.x;      // [0, 32768)
  int sel = i >> 14;
  int rem = i & 16383;
  int k = rem >> 7, n = rem & 127;
  const float* Ws = sel ? W2 : W1;
  ushort* Wd = sel ? Wt2 : Wt1;
  Wd[n*128 + k] = bf16u(Ws[rem]);
}

// C(bf16)[M,128] = maybe_relu(A) @ W, via MFMA 16x16x32 bf16.
// Wt = W^T as bf16 [n][k]. 64 rows/block, 4 waves (16-row strip each).
// gemm_bt pattern: a_frag from A rows, b_frag from Wt rows, identical k addressing.
template<bool BF16IN, bool RELU>
__global__ __launch_bounds__(256) void k_gemm_mfma(const void* __restrict__ Av,
                                                   const ushort* __restrict__ Wt,
                                                   __hip_bfloat16* __restrict__ C,
                                                   int M){
  __shared__ ushort sA[64*136];    // pad 136: 272B rows -> ~2-way conflicts
  __shared__ ushort sW[128*136];
  const int tid = threadIdx.x;
  const int row0 = blockIdx.x * 64;
  const int rowsHere = (M - row0 >= 64) ? 64 : (M - row0);

  // stage Wt (128 rows x 128 bf16 = 2048 x 16B)
  {
    const uint4* Wt4 = (const uint4*)Wt;
    for (int i = tid; i < 2048; i += 256){
      int r = i >> 4, c = i & 15;
      uint4 v = Wt4[i];
      *((uint4*)(sA + 0, (void)0, sW + r*136 + c*8)) = v;
    }
  }
  // stage A (convert to bf16 if needed; optional relu)
  if (BF16IN){
    const uint4* A4 = (const uint4*)((const ushort*)Av + (size_t)row0 * D);
    for (int i = tid; i < 64*16; i += 256){
      int r = i >> 4, c = i & 15;
      uint4 v = make_uint4(0,0,0,0);
      if (r < rowsHere) v = A4[i];
      if (RELU){ v.x = relu_bf2(v.x); v.y = relu_bf2(v.y);
                 v.z = relu_bf2(v.z); v.w = relu_bf2(v.w); }
      *((uint4*)(sA + r*136 + c*8)) = v;
    }
  } else {
    const float4* A4 = (const float4*)Av + (size_t)row0 * 32;
    for (int i = tid; i < 64*32; i += 256){
      int r = i >> 5, c = i & 31;
      float4 v = make_float4(0.f,0.f,0.f,0.f);
      if (r < rowsHere) v = A4[i];
      if (RELU){ v.x=relu(v.x); v.y=relu(v.y); v.z=relu(v.z); v.w=relu(v.w); }
      ushort4 p;
      p.x = bf16u(v.x); p.y = bf16u(v.y); p.z = bf16u(v.z); p.w = bf16u(v.w);
      *((ushort4*)(sA + r*136 + c*4)) = p;
    }
  }
  __syncthreads();

  const int wid  = tid >> 6;       // wave's 16-row strip
  const int lane = tid & 63;
  const int fr = lane & 15;        // A-row within strip / D-col within tile
  const int fq = lane >> 4;        // k-octet group / D-row group
  const ushort* aBase = sA + (wid*16 + fr)*136 + fq*8;
  const ushort* wBase = sW + fr*136 + fq*8;

  f32x4 acc0 = {0.f,0.f,0.f,0.f}, acc1 = acc0, acc2 = acc0, acc3 = acc0;
  f32x4 acc4 = acc0, acc5 = acc0, acc6 = acc0, acc7 = acc0;
  #pragma unroll
  for (int ks = 0; ks < 4; ++ks){
    bf16x8 a = *(const bf16x8*)(aBase + ks*32);
    bf16x8 b;
    b = *(const bf16x8*)(wBase + 0*16*136 + ks*32);
    acc0 = __builtin_amdgcn_mfma_f32_16x16x32_bf16(a, b, acc0, 0, 0, 0);
    b = *(const bf16x8*)(wBase + 1*16*136 + ks*32);
    acc1 = __builtin_amdgcn_mfma_f32_16x16x32_bf16(a, b, acc1, 0, 0, 0);
    b = *(const bf16x8*)(wBase + 2*16*136 + ks*32);
    acc2 = __builtin_amdgcn_mfma_f32_16x16x32_bf16(a, b, acc2, 0, 0, 0);
    b = *(const bf16x8*)(wBase + 3*16*136 + ks*32);
    acc3 = __builtin_amdgcn_mfma_f32_16x16x32_bf16(a, b, acc3, 0, 0, 0);
    b = *(const bf16x8*)(wBase + 4*16*136 + ks*32);
    acc4 = __builtin_amdgcn_mfma_f32_16x16x32_bf16(a, b, acc4, 0, 0, 0);
    b = *(const bf16x8*)(wBase + 5*16*136 + ks*32);
    acc5 = __builtin_amdgcn_mfma_f32_16x16x32_bf16(a, b, acc5, 0, 0, 0);
    b = *(const bf16x8*)(wBase + 6*16*136 + ks*32);
    acc6 = __builtin_amdgcn_mfma_f32_16x16x32_bf16(a, b, acc6, 0, 0, 0);
    b = *(const bf16x8*)(wBase + 7*16*136 + ks*32);
    acc7 = __builtin_amdgcn_mfma_f32_16x16x32_bf16(a, b, acc7, 0, 0, 0);
  }

  // epilogue: D col = fr (within tile), row = fq*4 + r (within strip)
  const int rbase = row0 + wid*16 + fq*4;
  #pragma unroll
  for (int r = 0; r < 4; ++r){
    int row = rbase + r;
    if (row < M){
      __hip_bfloat16* crow = C + (size_t)row*D + fr;
      crow[0*16]  = __float2bfloat16(acc0[r]);
      crow[1*16]  = __float2bfloat16(acc1[r]);
      crow[2*16]  = __float2bfloat16(acc2[r]);
      crow[3*16]  = __float2bfloat16(acc3[r]);
      crow[4*16]  = __float2bfloat16(acc4[r]);
      crow[5*16]  = __float2bfloat16(acc5[r]);
      crow[6*16]  = __float2bfloat16(acc6[r]);
      crow[7*16]  = __float2bfloat16(acc7[r]);
    }
  }
}

// bf16 gather core (R5 best config: 4 edges/step via 16-lane groups, unroll 2),
// edge meta {src, dinv[src]} from edat (no random scalar gather).
#define AGG_CORE_BF16                                                          \
  const int grp = lane >> 4;                                                   \
  const int q   = lane & 15;                                                   \
  float dn = dinv[node];                                                       \
  float4 aA0 = make_float4(0,0,0,0), aB0 = aA0, aA1 = aA0, aB1 = aA0;          \
  int beg = rowPtr[node], end = rowPtr[node+1];                                \
  for (int j = beg; j < end; j += 64){                                         \
    int rem = end - j;                                                         \
    int cnt = (rem < 64) ? rem : 64;                                           \
    int2 ed = make_int2(0, 0);                                                 \
    if (lane < cnt) ed = edat[j + lane];                                       \
    int T = (((cnt + 3) >> 2) + 1) & ~1;                                       \
    for (int t = 0; t < T; t += 2){                                            \
      _Pragma("unroll")                                                        \
      for (int u = 0; u < 2; ++u){                                             \
        int e = 4*(t+u) + grp;                                                 \
        int sb = __shfl(ed.x, e);                                              \
        float nb = __uint_as_float((unsigned)__shfl(ed.y, e)) * dn;            \
        uint4 hv = ((const uint4*)(h + (size_t)sb*D))[q];                      \
        float4& cA = u ? aA1 : aA0;                                            \
        float4& cB = u ? aB1 : aB0;                                            \
        cA.x += bf_lo(hv.x)*nb; cA.y += bf_hi(hv.x)*nb;                        \
        cA.z += bf_lo(hv.y)*nb; cA.w += bf_hi(hv.y)*nb;                        \
        cB.x += bf_lo(hv.z)*nb; cB.y += bf_hi(hv.z)*nb;                        \
        cB.z += bf_lo(hv.w)*nb; cB.w += bf_hi(hv.w)*nb;                        \
      }                                                                        \
    }                                                                          \
  }                                                                            \
  float4 rA, rB;                                                               \
  rA.x=aA0.x+aA1.x; rA.y=aA0.y+aA1.y; rA.z=aA0.z+aA1.z; rA.w=aA0.w+aA1.w;      \
  rB.x=aB0.x+aB1.x; rB.y=aB0.y+aB1.y; rB.z=aB0.z+aB1.z; rB.w=aB0.w+aB1.w;      \
  rA.x += __shfl_xor(rA.x,16,64); rA.y += __shfl_xor(rA.y,16,64);              \
  rA.z += __shfl_xor(rA.z,16,64); rA.w += __shfl_xor(rA.w,16,64);              \
  rB.x += __shfl_xor(rB.x,16,64); rB.y += __shfl_xor(rB.y,16,64);              \
  rB.z += __shfl_xor(rB.z,16,64); rB.w += __shfl_xor(rB.w,16,64);              \
  rA.x += __shfl_xor(rA.x,32,64); rA.y += __shfl_xor(rA.y,32,64);              \
  rA.z += __shfl_xor(rA.z,32,64); rA.w += __shfl_xor(rA.w,32,64);              \
  rB.x += __shfl_xor(rB.x,32,64); rB.y += __shfl_xor(rB.y,32,64);              \
  rB.z += __shfl_xor(rB.z,32,64); rB.w += __shfl_xor(rB.w,32,64);

// layer-1 agg: out(bf16)[node] = h*dinv^2 + b + gathered  (no relu here)
__global__ __launch_bounds__(256) void k_agg_csr(const ushort* __restrict__ h,
                                                 const int* __restrict__ rowPtr,
                                                 const int2* __restrict__ edat,
                                                 const float* __restrict__ dinv,
                                                 const float* __restrict__ b,
                                                 ushort* __restrict__ out, int n){
  int gid = blockIdx.x*256 + threadIdx.x;
  int node = gid >> 6;
  int lane = gid & 63;
  if (node >= n) return;
  AGG_CORE_BF16
  if (grp != 0) return;
  uint4 hs = ((const uint4*)(h + (size_t)node*D))[q];
  float sl = dn * dn;
  float4 bA = ((const float4*)b)[2*q];
  float4 bB = ((const float4*)b)[2*q + 1];
  float r[8];
  r[0] = rA.x + bf_lo(hs.x)*sl + bA.x;
  r[1] = rA.y + bf_hi(hs.x)*sl + bA.y;
  r[2] = rA.z + bf_lo(hs.y)*sl + bA.z;
  r[3] = rA.w + bf_hi(hs.y)*sl + bA.w;
  r[4] = rB.x + bf_lo(hs.z)*sl + bB.x;
  r[5] = rB.y + bf_hi(hs.z)*sl + bB.y;
  r[6] = rB.z + bf_lo(hs.w)*sl + bB.z;
  r[7] = rB.w + bf_hi(hs.w)*sl + bB.w;
  union Pack { uint4 u; __hip_bfloat16 b[8]; } p;
  #pragma unroll
  for (int i = 0; i < 8; ++i) p.b[i] = __float2bfloat16(r[i]);
  ((uint4*)(out + (size_t)node*D))[q] = p.u;
}

// layer-2 agg fused with head: relu(agg) @ Wl + bl -> log_softmax
__global__ __launch_bounds__(256) void k_agg_head(const ushort* __restrict__ h,
                                                  const int* __restrict__ rowPtr,
                                                  const int2* __restrict__ edat,
                                                  const float* __restrict__ dinv,
                                                  const float* __restrict__ b,
                                                  const float* __restrict__ Wl,
                                                  const float* __restrict__ bl,
                                                  float* __restrict__ out, int n){
  int gid = blockIdx.x*256 + threadIdx.x;
  int node = gid >> 6;
  int lane = gid & 63;
  if (node >= n) return;
  AGG_CORE_BF16
  if (grp != 0) return;
  uint4 hs = ((const uint4*)(h + (size_t)node*D))[q];
  float sl = dn * dn;
  float4 bA = ((const float4*)b)[2*q];
  float4 bB = ((const float4*)b)[2*q + 1];
  float r[8];
  r[0] = relu(rA.x + bf_lo(hs.x)*sl + bA.x);
  r[1] = relu(rA.y + bf_hi(hs.x)*sl + bA.y);
  r[2] = relu(rA.z + bf_lo(hs.y)*sl + bA.z);
  r[3] = relu(rA.w + bf_hi(hs.y)*sl + bA.w);
  r[4] = relu(rB.x + bf_lo(hs.z)*sl + bB.x);
  r[5] = relu(rB.y + bf_hi(hs.z)*sl + bB.y);
  r[6] = relu(rB.z + bf_lo(hs.w)*sl + bB.z);
  r[7] = relu(rB.w + bf_hi(hs.w)*sl + bB.w);
  float lacc[NCLS];
  #pragma unroll
  for (int c = 0; c < NCLS; ++c){
    float a = 0.f;
    #pragma unroll
    for (int i = 0; i < 8; ++i) a += r[i] * Wl[(8*q + i)*NCLS + c];
    lacc[c] = a;
  }
  #pragma unroll
  for (int c = 0; c < NCLS; ++c){
    #pragma unroll
    for (int off = 8; off >= 1; off >>= 1)
      lacc[c] += __shfl_xor(lacc[c], off, 16);
    lacc[c] += bl[c];
  }
  float m = lacc[0];
  #pragma unroll
  for (int c = 1; c < NCLS; ++c) m = fmaxf(m, lacc[c]);
  float se = 0.f;
  #pragma unroll
  for (int c = 0; c < NCLS; ++c) se += expf(lacc[c] - m);
  float lse = m + logf(se);
  if (q < NCLS){
    float v = lacc[0];
    #pragma unroll
    for (int c = 1; c < NCLS; ++c) if (q == c) v = lacc[c];
    out[(size_t)node*NCLS + q] = v - lse;
  }
}

extern "C" void kernel_launch(void* const* d_in, const int* in_sizes, int n_in,
                              void* d_out, int out_size, void* d_ws, size_t ws_size,
                              hipStream_t stream){
  const float* x  = (const float*)d_in[0];
  const int*   ei = (const int*)d_in[1];
  const float* W1 = (const float*)d_in[2];
  const float* b1 = (const float*)d_in[3];
  const float* W2 = (const float*)d_in[4];
  const float* b2 = (const float*)d_in[5];
  const float* Wl = (const float*)d_in[6];
  const float* bl = (const float*)d_in[7];
  float* out = (float*)d_out;

  const int N = in_sizes[0] / D;     // 50000
  const int E = in_sizes[1] / 2;     // 800000
  const int* src = ei;
  const int* dst = ei + E;

  char* ws = (char*)d_ws;
  size_t off = 0;
  ushort* h1    = (ushort*)(ws + off); off += (size_t)N*D*2;
  ushort* g1    = (ushort*)(ws + off); off += (size_t)N*D*2;
  ushort* h2    = (ushort*)(ws + off); off += (size_t)N*D*2;
  ushort* Wt1   = (ushort*)(ws + off); off += (size_t)128*128*2;
  ushort* Wt2   = (ushort*)(ws + off); off += (size_t)128*128*2;
  int*   counts = (int*)(ws + off);    off += (size_t)N*4;
  int*   cursor = (int*)(ws + off);    off += (size_t)N*4;
  int*   rowPtr = (int*)(ws + off);    off += (size_t)(N+2)*4;  // pad for 8B align
  float* dinv   = (float*)(ws + off);  off += (size_t)N*4;
  int*   bsum   = (int*)(ws + off);    off += (size_t)256*4;
  int2*  edat   = (int2*)(ws + off);   off += (size_t)E*8;

  const int nbN   = (N + 255)/256;   // 196 <= 256
  const int nb2N  = (2*N + 255)/256;
  const int nbE   = (E + 255)/256;
  const int gemmB = (N + 63)/64;     // 782
  const int aggB  = (N + 3)/4;       // 1 wave per node

  // CSR build + weight transpose
  k_zero_i32<<<nb2N, 256, 0, stream>>>(counts, 2*N);           // counts + cursor
  k_hist<<<nbE, 256, 0, stream>>>(dst, counts, E);
  k_scan1<<<nbN, 256, 0, stream>>>(counts, rowPtr, bsum, dinv, N);
  k_scan2<<<1, 256, 0, stream>>>(bsum, rowPtr, nbN, N);
  k_scan3<<<nbN, 256, 0, stream>>>(bsum, rowPtr, N);
  k_scatter<<<nbE, 256, 0, stream>>>(src, dst, rowPtr, dinv, cursor, edat, E);
  k_cvtW<<<128, 256, 0, stream>>>(W1, W2, Wt1, Wt2);

  // layer 1: MFMA GEMM (f32 x -> bf16), agg -> g1 (bf16, no relu)
  k_gemm_mfma<false,false><<<gemmB, 256, 0, stream>>>(x, Wt1, (__hip_bfloat16*)h1, N);
  k_agg_csr<<<aggB, 256, 0, stream>>>(h1, rowPtr, edat, dinv, b1, g1, N);

  // layer 2: relu fused into GEMM staging; head fused into aggregation
  k_gemm_mfma<true,true><<<gemmB, 256, 0, stream>>>(g1, Wt2, (__hip_bfloat16*)h2, N);
  k_agg_head<<<aggB, 256, 0, stream>>>(h2, rowPtr, edat, dinv, b2, Wl, bl, out, N);
}